// Round 2
// baseline (237.237 us; speedup 1.0000x reference)
//
#include <hip/hip_runtime.h>
#include <math.h>

typedef __attribute__((ext_vector_type(8))) _Float16 half8;
typedef __attribute__((ext_vector_type(4))) float    f32x4;

constexpr int D_DIM = 2048;
constexpr int NEXP  = 64;
constexpr int TOPK  = 8;
constexpr int NTOK  = 16384;        // B*S
constexpr int TM    = 16;           // tokens per WG
constexpr int BK    = 256;          // K per staged chunk (8 MFMA ksteps)
constexpr int NCH   = D_DIM / BK;   // 8 chunks
constexpr int OSTR  = 132;          // logit tile row stride (floats)
constexpr float WSCALE  = 4096.0f;
constexpr float INV_WSC = 1.0f / 4096.0f;

__device__ __forceinline__ unsigned short f16b(float x) {
    _Float16 h = (_Float16)x;                       // v_cvt_f16_f32 (RNE)
    return __builtin_bit_cast(unsigned short, h);
}
__device__ __forceinline__ float f16tof(unsigned short b) {
    return (float)__builtin_bit_cast(_Float16, b);
}

// ---------------------------------------------------------------------------
// K1 (unchanged): W*4096 (gate rows 0..63, noise rows 64..127) split fp16
// hi/lo, packed B-fragment-linear:
//   [kstep32 (stride 8192)][ntile (stride 1024)]{ hi 512 | lo 512 }
//   lane l holds B[k = ks*32 + (l>>4)*8 + j][n = T*16 + (l&15)]
// ---------------------------------------------------------------------------
__global__ void prep_w(const float* __restrict__ Wg, const float* __restrict__ Wn,
                       unsigned short* __restrict__ wsB)
{
    const int idx = blockIdx.x * blockDim.x + threadIdx.x;   // 0..32767
    const int n   = idx >> 8;      // output row 0..127
    const int K8  = idx & 255;     // k-octet
    const float* src = (n < 64) ? (Wg + (size_t)n * D_DIM)
                                : (Wn + (size_t)(n - 64) * D_DIM);
    float4 a = *reinterpret_cast<const float4*>(src + K8 * 8);
    float4 b = *reinterpret_cast<const float4*>(src + K8 * 8 + 4);

    float v[8] = {a.x, a.y, a.z, a.w, b.x, b.y, b.z, b.w};
    union { unsigned short u[8]; half8 s; } H, L;
#pragma unroll
    for (int j = 0; j < 8; ++j) {
        float xs = v[j] * WSCALE;
        unsigned short h = f16b(xs);
        H.u[j] = h;
        L.u[j] = f16b(xs - f16tof(h));
    }
    const int l = ((K8 & 3) * 16) + (n & 15);
    const size_t base = (size_t)(K8 >> 2) * 8192 + (size_t)(n >> 4) * 1024 + (size_t)l * 8;
    *reinterpret_cast<half8*>(wsB + base)       = H.s;
    *reinterpret_cast<half8*>(wsB + base + 512) = L.s;
}

// ---------------------------------------------------------------------------
// K2 v3: occupancy-oriented. TM=16 tokens/WG, 1024 WGs -> 4 WGs/CU
// (32 waves/CU, 8/SIMD) with VGPR forced <=64. 8 waves = 8 n-tiles (1 each).
// BK=256 (8 ksteps, 8 barriers). Per-thread staging: full k-octet -> 16B
// LDS writes, XOR bank swizzle. B ring depth 2 ksteps in registers.
// LDS: 2 stage bufs x 8192 ushorts (32 KB) union'd with 16x132 f32 logits.
// ---------------------------------------------------------------------------
__global__ __launch_bounds__(512, 8)
void noisy_topk_router(const float* __restrict__ hs,
                       const unsigned short* __restrict__ wsB,
                       const float* __restrict__ nz,
                       float* __restrict__ out)
{
    __shared__ __align__(16) char smem[32768];
    unsigned short* stage  = reinterpret_cast<unsigned short*>(smem);
    float*          logits = reinterpret_cast<float*>(smem);

    const int tid  = threadIdx.x;
    const int lane = tid & 63;
    const int w    = tid >> 6;          // wave id = n-tile (experts w*16..+15)
    const int t0   = blockIdx.x * TM;

    // --- per-lane A-fragment read decomposition ---
    const int j0r = lane >> 4;          // k-octet within kstep
    const int mr  = lane & 15;          // token row

    // --- staging role: thread t -> row r (32 thr/row), k-octet q (0..31) ---
    const int r    = tid >> 5;          // 0..15
    const int q    = tid & 31;          // octet within chunk256
    const int ks_s = q >> 2;            // kstep within chunk (0..7)
    const int j0s  = q & 3;
    const int fs   = (ks_s & 3) | ((j0s & 1) << 2);
    const int wroff = ks_s * 512 + (j0s * 16 + (r ^ fs)) * 8;
    const float* hrow = hs + (size_t)(t0 + r) * D_DIM + q * 8;

    // --- B base: wsB + kk*8192 + ntile*1024 + lane*8 ; ntile = w ---
    const unsigned short* bbase = wsB + (size_t)w * 1024 + (size_t)lane * 8;

    f32x4 accP0 = (f32x4){0.f, 0.f, 0.f, 0.f};
    f32x4 accP1 = (f32x4){0.f, 0.f, 0.f, 0.f};
    f32x4 accX0 = (f32x4){0.f, 0.f, 0.f, 0.f};
    f32x4 accX1 = (f32x4){0.f, 0.f, 0.f, 0.f};

    // --- B ring prefetch, 2 ksteps deep: slot = kk&1 ---
    half8 bh[2], bl[2];
#pragma unroll
    for (int s = 0; s < 2; ++s) {
        const unsigned short* bp = bbase + (size_t)s * 8192;
        bh[s] = *reinterpret_cast<const half8*>(bp);
        bl[s] = *reinterpret_cast<const half8*>(bp + 512);
    }

    auto cvt_write = [&](float4 a, float4 b, unsigned short* buf) {
        float v[8] = {a.x, a.y, a.z, a.w, b.x, b.y, b.z, b.w};
        union { unsigned short u[8]; half8 s; } H, L;
#pragma unroll
        for (int j = 0; j < 8; ++j) {
            unsigned short h = f16b(v[j]);
            H.u[j] = h;
            L.u[j] = f16b(v[j] - f16tof(h));
        }
        *reinterpret_cast<half8*>(buf + wroff)        = H.s;
        *reinterpret_cast<half8*>(buf + wroff + 4096) = L.s;
    };

    // prologue: stage chunk 0
    {
        float4 a = *reinterpret_cast<const float4*>(hrow);
        float4 b = *reinterpret_cast<const float4*>(hrow + 4);
        cvt_write(a, b, stage);
    }
    __syncthreads();

    for (int c = 0; c < NCH; ++c) {
        // hs prefetch for c+1 (budget ~ one chunk body)
        float4 pa, pb;
        if (c + 1 < NCH) {
            pa = *reinterpret_cast<const float4*>(hrow + (c + 1) * BK);
            pb = *reinterpret_cast<const float4*>(hrow + (c + 1) * BK + 4);
        }
        const unsigned short* sb = stage + (c & 1) * 8192;

#pragma unroll
        for (int ks = 0; ks < 8; ++ks) {
            const int kk   = c * 8 + ks;
            const int slot = ks & 1;               // == kk&1 (8c even)
            const int fr   = (ks & 3) | ((j0r & 1) << 2);
            const int off  = ks * 512 + (j0r * 16 + (mr ^ fr)) * 8;
            half8 ahi = *reinterpret_cast<const half8*>(sb + off);
            half8 alo = *reinterpret_cast<const half8*>(sb + off + 4096);
            if ((ks & 1) == 0)
                accP0 = __builtin_amdgcn_mfma_f32_16x16x32_f16(ahi, bh[slot], accP0, 0, 0, 0);
            else
                accP1 = __builtin_amdgcn_mfma_f32_16x16x32_f16(ahi, bh[slot], accP1, 0, 0, 0);
            accX0 = __builtin_amdgcn_mfma_f32_16x16x32_f16(ahi, bl[slot], accX0, 0, 0, 0);
            accX1 = __builtin_amdgcn_mfma_f32_16x16x32_f16(alo, bh[slot], accX1, 0, 0, 0);
            // refill this slot for kstep kk+2
            if (kk + 2 < 64) {
                const unsigned short* bp2 = bbase + (size_t)(kk + 2) * 8192;
                bh[slot] = *reinterpret_cast<const half8*>(bp2);
                bl[slot] = *reinterpret_cast<const half8*>(bp2 + 512);
            }
        }

        if (c + 1 < NCH)
            cvt_write(pa, pb, stage + ((c + 1) & 1) * 8192);
        __syncthreads();
    }

    // ---- epilogue: accs -> logit tile (stage region is dead now) ----
    {
        const int colb = w * 16 + mr;
        const int rowb = j0r * 4;
#pragma unroll
        for (int rr = 0; rr < 4; ++rr)
            logits[(rowb + rr) * OSTR + colb] =
                (accP0[rr] + accP1[rr] + accX0[rr] + accX1[rr]) * INV_WSC;
    }
    __syncthreads();

    // ---- wave-parallel epilogue: wave w owns tokens w*2, w*2+1,
    //      expert-per-lane (lane = expert e) ----
    float* gout = out + (size_t)NTOK * TOPK * 2;
    for (int tt = 0; tt < 2; ++tt) {
        const int tl  = w * 2 + tt;
        const int tok = t0 + tl;
        float gsc = logits[tl * OSTR + lane];
        float nl  = logits[tl * OSTR + 64 + lane];
        float nzv = nz[(size_t)tok * NEXP + lane];
        float sp  = fmaxf(nl, 0.0f) + log1pf(expf(-fabsf(nl)));   // softplus
        float le  = fmaf(nzv, sp, gsc);

        float mx = le;
#pragma unroll
        for (int d = 32; d > 0; d >>= 1) mx = fmaxf(mx, __shfl_xor(mx, d));
        float pe = expf(le - mx);
        float s  = pe;
#pragma unroll
        for (int d = 32; d > 0; d >>= 1) s += __shfl_xor(s, d);
        float g = pe * (1.0f / s);

        gout[(size_t)tok * NEXP + lane] = g;

        // top-8 by repeated wave argmax; tie-break: lowest index
        float v = g;
        float keepv = 0.0f;
        int   keepi = 0;
#pragma unroll
        for (int it = 0; it < TOPK; ++it) {
            float m  = v;
            int   mi = lane;
#pragma unroll
            for (int d = 32; d > 0; d >>= 1) {
                float om = __shfl_xor(m, d);
                int   oi = __shfl_xor(mi, d);
                bool take = (om > m) || (om == m && oi < mi);
                m  = take ? om : m;
                mi = take ? oi : mi;
            }
            if (lane == it) { keepv = m; keepi = mi; }
            if (lane == mi) v = -1.0f;      // extracted; gates>0 so never re-wins
        }
        if (lane < TOPK) {
            out[(size_t)tok * TOPK + lane] = keepv;
            out[(size_t)NTOK * TOPK + (size_t)tok * TOPK + lane] = (float)keepi;
        }
    }
}

extern "C" void kernel_launch(void* const* d_in, const int* in_sizes, int n_in,
                              void* d_out, int out_size, void* d_ws, size_t ws_size,
                              hipStream_t stream) {
    const float* hs = (const float*)d_in[0];   // [4,4096,2048]
    const float* Wg = (const float*)d_in[1];   // [64,2048]
    const float* Wn = (const float*)d_in[2];   // [64,2048]
    const float* nz = (const float*)d_in[3];   // [4,4096,64]
    float* out = (float*)d_out;
    unsigned short* wsB = (unsigned short*)d_ws;   // 1 MB B-fragment pack

    prep_w<<<64, 512, 0, stream>>>(Wg, Wn, wsB);
    noisy_topk_router<<<NTOK / TM, 512, 0, stream>>>(hs, wsB, nz, out);
}

// Round 3
// 229.946 us; speedup vs baseline: 1.0317x; 1.0317x over previous
//
#include <hip/hip_runtime.h>
#include <math.h>

typedef __attribute__((ext_vector_type(8))) _Float16 half8;
typedef __attribute__((ext_vector_type(4))) float    f32x4;

constexpr int D_DIM = 2048;
constexpr int NEXP  = 64;
constexpr int TOPK  = 8;
constexpr int NTOK  = 16384;        // B*S
constexpr int TM    = 32;           // tokens per WG
constexpr int BK    = 128;          // K per staged chunk (4 MFMA ksteps)
constexpr int NCH   = D_DIM / BK;   // 16 chunks
constexpr int OSTR  = 132;          // logit tile row stride (floats)
constexpr float WSCALE  = 4096.0f;
constexpr float INV_WSC = 1.0f / 4096.0f;

__device__ __forceinline__ unsigned short f16b(float x) {
    _Float16 h = (_Float16)x;                       // v_cvt_f16_f32 (RNE)
    return __builtin_bit_cast(unsigned short, h);
}
__device__ __forceinline__ float f16tof(unsigned short b) {
    return (float)__builtin_bit_cast(_Float16, b);
}

// ---------------------------------------------------------------------------
// K1 (unchanged): W*4096 (gate rows 0..63, noise rows 64..127) split fp16
// hi/lo, packed B-fragment-linear:
//   [kstep32 (stride 8192)][ntile (stride 1024)]{ hi 512 | lo 512 }
//   lane l holds B[k = ks*32 + (l>>4)*8 + j][n = T*16 + (l&15)]
// ---------------------------------------------------------------------------
__global__ void prep_w(const float* __restrict__ Wg, const float* __restrict__ Wn,
                       unsigned short* __restrict__ wsB)
{
    const int idx = blockIdx.x * blockDim.x + threadIdx.x;   // 0..32767
    const int n   = idx >> 8;      // output row 0..127
    const int K8  = idx & 255;     // k-octet
    const float* src = (n < 64) ? (Wg + (size_t)n * D_DIM)
                                : (Wn + (size_t)(n - 64) * D_DIM);
    float4 a = *reinterpret_cast<const float4*>(src + K8 * 8);
    float4 b = *reinterpret_cast<const float4*>(src + K8 * 8 + 4);

    float v[8] = {a.x, a.y, a.z, a.w, b.x, b.y, b.z, b.w};
    union { unsigned short u[8]; half8 s; } H, L;
#pragma unroll
    for (int j = 0; j < 8; ++j) {
        float xs = v[j] * WSCALE;
        unsigned short h = f16b(xs);
        H.u[j] = h;
        L.u[j] = f16b(xs - f16tof(h));
    }
    const int l = ((K8 & 3) * 16) + (n & 15);
    const size_t base = (size_t)(K8 >> 2) * 8192 + (size_t)(n >> 4) * 1024 + (size_t)l * 8;
    *reinterpret_cast<half8*>(wsB + base)       = H.s;
    *reinterpret_cast<half8*>(wsB + base + 512) = L.s;
}

// ---------------------------------------------------------------------------
// K2 v4: vmcnt-chain fix. Per chunk the ISSUE ORDER is
//   [8 B loads for chunk c (L2)] -> [hs prefetch for c+1 (HBM)] -> MFMA body
// so B consumption never waits behind the HBM prefetch (in-order vmcnt
// retire). sched_barrier(0) pins the order. Wave w = n-tile w, 2 m-tiles
// (halves wsB L2 traffic to 512 MB). BK=128, B single-buffered per chunk.
// LDS: 2 stage bufs x 8192 ushorts (32 KB) union'd with 32x132 f32 logits.
// ---------------------------------------------------------------------------
__global__ __launch_bounds__(512, 4)
void noisy_topk_router(const float* __restrict__ hs,
                       const unsigned short* __restrict__ wsB,
                       const float* __restrict__ nz,
                       float* __restrict__ out)
{
    __shared__ __align__(16) char smem[32768];
    unsigned short* stage  = reinterpret_cast<unsigned short*>(smem);
    float*          logits = reinterpret_cast<float*>(smem);

    const int tid  = threadIdx.x;
    const int lane = tid & 63;
    const int w    = tid >> 6;          // wave id = n-tile (experts w*16..+15)
    const int t0   = blockIdx.x * TM;

    // --- per-lane A-fragment read decomposition ---
    const int j0r = lane >> 4;          // k-octet within kstep
    const int mr  = lane & 15;          // token row within m-tile

    // --- staging role: thread t -> row r (0..31), k-octet q (0..15) ---
    const int r    = tid >> 4;
    const int q    = tid & 15;
    const int ks_s = q >> 2;            // kstep within chunk (0..3)
    const int j0s  = q & 3;
    const int ms   = r & 15;
    const int mts  = r >> 4;
    const int fs   = ks_s | ((j0s & 1) << 2);
    const int wroff = (mts * 4 + ks_s) * 512 + (j0s * 16 + (ms ^ fs)) * 8;
    const float* hrow = hs + (size_t)(t0 + r) * D_DIM + q * 8;

    // --- B base: wsB + kk*8192 + ntile*1024 + lane*8 ; ntile = w ---
    const unsigned short* bbase = wsB + (size_t)w * 1024 + (size_t)lane * 8;

    f32x4 accP0[2], accP1[2], accX0[2], accX1[2];   // [mt]
#pragma unroll
    for (int mt = 0; mt < 2; ++mt) {
        accP0[mt] = (f32x4){0.f, 0.f, 0.f, 0.f};
        accP1[mt] = (f32x4){0.f, 0.f, 0.f, 0.f};
        accX0[mt] = (f32x4){0.f, 0.f, 0.f, 0.f};
        accX1[mt] = (f32x4){0.f, 0.f, 0.f, 0.f};
    }

    auto cvt_write = [&](float4 a, float4 b, unsigned short* buf) {
        float v[8] = {a.x, a.y, a.z, a.w, b.x, b.y, b.z, b.w};
        union { unsigned short u[8]; half8 s; } H, L;
#pragma unroll
        for (int j = 0; j < 8; ++j) {
            unsigned short h = f16b(v[j]);
            H.u[j] = h;
            L.u[j] = f16b(v[j] - f16tof(h));
        }
        *reinterpret_cast<half8*>(buf + wroff)        = H.s;
        *reinterpret_cast<half8*>(buf + wroff + 4096) = L.s;
    };

    // prologue: stage chunk 0 (load fully consumed before first barrier)
    {
        float4 a = *reinterpret_cast<const float4*>(hrow);
        float4 b = *reinterpret_cast<const float4*>(hrow + 4);
        cvt_write(a, b, stage);
    }
    __syncthreads();

#pragma unroll 1
    for (int c = 0; c < NCH; ++c) {
        // (1) B loads for THIS chunk — issued before the hs prefetch so their
        //     vmcnt retirement is independent of the HBM load.
        half8 bh[4], bl[4];
#pragma unroll
        for (int ks = 0; ks < 4; ++ks) {
            const unsigned short* bp = bbase + (size_t)(c * 4 + ks) * 8192;
            bh[ks] = *reinterpret_cast<const half8*>(bp);
            bl[ks] = *reinterpret_cast<const half8*>(bp + 512);
        }
        __builtin_amdgcn_sched_barrier(0);

        // (2) hs prefetch for c+1 (newest in queue; only cvt_write waits on it)
        float4 pa, pb;
        if (c + 1 < NCH) {
            pa = *reinterpret_cast<const float4*>(hrow + (c + 1) * BK);
            pb = *reinterpret_cast<const float4*>(hrow + (c + 1) * BK + 4);
        }
        __builtin_amdgcn_sched_barrier(0);

        // (3) MFMA body
        const unsigned short* sb = stage + (c & 1) * 8192;
#pragma unroll
        for (int ks = 0; ks < 4; ++ks) {
            const int fr = ks | ((j0r & 1) << 2);
#pragma unroll
            for (int mt = 0; mt < 2; ++mt) {
                const int off = (mt * 4 + ks) * 512 + (j0r * 16 + (mr ^ fr)) * 8;
                half8 ahi = *reinterpret_cast<const half8*>(sb + off);
                half8 alo = *reinterpret_cast<const half8*>(sb + off + 4096);
                if ((ks & 1) == 0)
                    accP0[mt] = __builtin_amdgcn_mfma_f32_16x16x32_f16(ahi, bh[ks], accP0[mt], 0, 0, 0);
                else
                    accP1[mt] = __builtin_amdgcn_mfma_f32_16x16x32_f16(ahi, bh[ks], accP1[mt], 0, 0, 0);
                accX0[mt] = __builtin_amdgcn_mfma_f32_16x16x32_f16(ahi, bl[ks], accX0[mt], 0, 0, 0);
                accX1[mt] = __builtin_amdgcn_mfma_f32_16x16x32_f16(alo, bh[ks], accX1[mt], 0, 0, 0);
            }
        }

        // (4) stage c+1, swap, one barrier per chunk
        if (c + 1 < NCH)
            cvt_write(pa, pb, stage + ((c + 1) & 1) * 8192);
        __syncthreads();
    }

    // ---- epilogue: accs -> logit tile (stage region is dead now) ----
    {
        const int colb = w * 16 + mr;
#pragma unroll
        for (int mt = 0; mt < 2; ++mt) {
            const int rowb = mt * 16 + j0r * 4;
#pragma unroll
            for (int rr = 0; rr < 4; ++rr)
                logits[(rowb + rr) * OSTR + colb] =
                    (accP0[mt][rr] + accP1[mt][rr] + accX0[mt][rr] + accX1[mt][rr]) * INV_WSC;
        }
    }
    __syncthreads();

    // ---- wave-parallel epilogue: wave w owns tokens w*4..w*4+3,
    //      expert-per-lane (lane = expert e) ----
    float* gout = out + (size_t)NTOK * TOPK * 2;
    for (int tt = 0; tt < 4; ++tt) {
        const int tl  = w * 4 + tt;
        const int tok = t0 + tl;
        float gsc = logits[tl * OSTR + lane];
        float nl  = logits[tl * OSTR + 64 + lane];
        float nzv = nz[(size_t)tok * NEXP + lane];
        float sp  = fmaxf(nl, 0.0f) + log1pf(expf(-fabsf(nl)));   // softplus
        float le  = fmaf(nzv, sp, gsc);

        float mx = le;
#pragma unroll
        for (int d = 32; d > 0; d >>= 1) mx = fmaxf(mx, __shfl_xor(mx, d));
        float pe = expf(le - mx);
        float s  = pe;
#pragma unroll
        for (int d = 32; d > 0; d >>= 1) s += __shfl_xor(s, d);
        float g = pe * (1.0f / s);

        gout[(size_t)tok * NEXP + lane] = g;

        // top-8 by repeated wave argmax; tie-break: lowest index
        float v = g;
        float keepv = 0.0f;
        int   keepi = 0;
#pragma unroll
        for (int it = 0; it < TOPK; ++it) {
            float m  = v;
            int   mi = lane;
#pragma unroll
            for (int d = 32; d > 0; d >>= 1) {
                float om = __shfl_xor(m, d);
                int   oi = __shfl_xor(mi, d);
                bool take = (om > m) || (om == m && oi < mi);
                m  = take ? om : m;
                mi = take ? oi : mi;
            }
            if (lane == it) { keepv = m; keepi = mi; }
            if (lane == mi) v = -1.0f;      // extracted; gates>0 so never re-wins
        }
        if (lane < TOPK) {
            out[(size_t)tok * TOPK + lane] = keepv;
            out[(size_t)NTOK * TOPK + (size_t)tok * TOPK + lane] = (float)keepi;
        }
    }
}

extern "C" void kernel_launch(void* const* d_in, const int* in_sizes, int n_in,
                              void* d_out, int out_size, void* d_ws, size_t ws_size,
                              hipStream_t stream) {
    const float* hs = (const float*)d_in[0];   // [4,4096,2048]
    const float* Wg = (const float*)d_in[1];   // [64,2048]
    const float* Wn = (const float*)d_in[2];   // [64,2048]
    const float* nz = (const float*)d_in[3];   // [4,4096,64]
    float* out = (float*)d_out;
    unsigned short* wsB = (unsigned short*)d_ws;   // 1 MB B-fragment pack

    prep_w<<<64, 512, 0, stream>>>(Wg, Wn, wsB);
    noisy_topk_router<<<NTOK / TM, 512, 0, stream>>>(hs, wsB, nz, out);
}